// Round 3
// baseline (178.023 us; speedup 1.0000x reference)
//
#include <hip/hip_runtime.h>

#define C_DIM 256
#define CQK   32
#define N_DIM 4096
#define B_DIM 2

typedef __attribute__((ext_vector_type(8))) short bf16x8;
typedef __attribute__((ext_vector_type(4))) float f32x4;

__device__ __forceinline__ unsigned short f2bf(float f) {
    union { float f; unsigned u; } v; v.f = f;
    unsigned r = v.u + 0x7FFFu + ((v.u >> 16) & 1u);   // RNE
    return (unsigned short)(r >> 16);
}
__device__ __forceinline__ unsigned pk2(float a, float b) {
    return (unsigned)f2bf(a) | ((unsigned)f2bf(b) << 16);
}
// truncating pack via v_perm_b32 (1 VALU op): low16 = bf16_trunc(a), high = b
__device__ __forceinline__ unsigned pk2t(float a, float b) {
    union { float f; unsigned u; } ua, ub; ua.f = a; ub.f = b;
    return __builtin_amdgcn_perm(ub.u, ua.u, 0x07060302u);
}
#define EXP2(x) __builtin_amdgcn_exp2f(x)
#define MFMA(A, B, C) __builtin_amdgcn_mfma_f32_16x16x32_bf16((A), (B), (C), 0, 0, 0)

// ---------------------------------------------------------------------------
// Kernel 0: convert W (q|k|v rows, 320x256) to bf16 + gather biases.
// q rows (and q bias) pre-scaled by log2(e) so attn uses raw 2^x.
// ---------------------------------------------------------------------------
__global__ __launch_bounds__(256) void wconv(
    const float* __restrict__ q_w, const float* __restrict__ q_b,
    const float* __restrict__ k_w, const float* __restrict__ k_b,
    const float* __restrict__ v_w, const float* __restrict__ v_b,
    unsigned short* __restrict__ wbf, float* __restrict__ biasf)
{
    const float LOG2E = 1.4426950408889634f;
    int o = blockIdx.x, c = threadIdx.x;
    float w;
    if (o < 32)       w = q_w[o * C_DIM + c] * LOG2E;
    else if (o < 64)  w = k_w[(o - 32) * C_DIM + c];
    else              w = v_w[(o - 64) * C_DIM + c];
    wbf[o * C_DIM + c] = f2bf(w);
    if (c == 0) biasf[o] = (o < 32) ? q_b[o] * LOG2E
                         : (o < 64) ? k_b[o - 32] : v_b[o - 64];
}

// ---------------------------------------------------------------------------
// Kernel 1: QKV projection via MFMA, 16-col n-tiles.
// V stored TILED as [b][cs(4)][jt(128)][c'(64)][j'(32)] bf16 — the exact 4KB
// tile one attn wave consumes per iteration (full-128B-line loads, proven R2).
// ---------------------------------------------------------------------------
__global__ __launch_bounds__(256, 2) void qkv_proj(
    const float* __restrict__ x, const unsigned short* __restrict__ wbf,
    const float* __restrict__ biasf,
    unsigned short* __restrict__ qT, unsigned short* __restrict__ kT,
    unsigned short* __restrict__ vbf)
{
    __shared__ __align__(16) unsigned short xsT[16 * 264];     // [n][c] bf16
    __shared__ __align__(16) unsigned short qkbuf[2][16 * 36]; // q/k bounce
    __shared__ __align__(16) unsigned short vbb[256 * 20];     // v bounce, stride 20
    const int t  = threadIdx.x;
    const int b  = blockIdx.x >> 8;
    const int n0 = (blockIdx.x & 255) * 16;

    {
        int n4 = t & 3, cq = t >> 2;   // cq 0..63
        const float* xp = x + ((size_t)(b * C_DIM + cq * 4)) * N_DIM + n0 + n4 * 4;
        float4 r0 = *(const float4*)xp;
        float4 r1 = *(const float4*)(xp + N_DIM);
        float4 r2 = *(const float4*)(xp + 2 * N_DIM);
        float4 r3 = *(const float4*)(xp + 3 * N_DIM);
        float a0[4], a1[4], a2[4], a3[4];
        *(float4*)a0 = r0; *(float4*)a1 = r1; *(float4*)a2 = r2; *(float4*)a3 = r3;
        #pragma unroll
        for (int k = 0; k < 4; ++k) {
            uint2 pw;
            pw.x = pk2(a0[k], a1[k]);
            pw.y = pk2(a2[k], a3[k]);
            *(uint2*)&xsT[(n4 * 4 + k) * 264 + cq * 4] = pw;
        }
    }
    __syncthreads();

    const int w = t >> 6, lid = t & 63, lr = lid & 15, lq = lid >> 4;
    f32x4 acc[5] = {};
    #pragma unroll
    for (int ks = 0; ks < 8; ++ks) {
        bf16x8 xb = *(const bf16x8*)&xsT[lr * 264 + ks * 32 + lq * 8];
        #pragma unroll
        for (int u = 0; u < 5; ++u) {
            int gm = w * 5 + u;
            bf16x8 af = *(const bf16x8*)&wbf[(gm * 16 + lr) * C_DIM + ks * 32 + lq * 8];
            acc[u] = MFMA(af, xb, acc[u]);
        }
    }
    #pragma unroll
    for (int u = 0; u < 5; ++u) {
        int gm = w * 5 + u;
        float bv[4];
        *(float4*)bv = *(const float4*)&biasf[gm * 16 + lq * 4];
        if (gm >= 4) {
            int vc = (gm - 4) * 16 + lq * 4;
            #pragma unroll
            for (int r = 0; r < 4; ++r)
                vbb[(vc + r) * 20 + lr] = f2bf(acc[u][r] + bv[r]);
        } else {
            int sel = gm >> 1, half = gm & 1;   // wave 0 only
            uint2 pw;
            pw.x = pk2(acc[u][0] + bv[0], acc[u][1] + bv[1]);
            pw.y = pk2(acc[u][2] + bv[2], acc[u][3] + bv[3]);
            *(uint2*)&qkbuf[sel][lr * 36 + half * 16 + lq * 4] = pw;
        }
    }
    __syncthreads();
    if (t < 128) {
        int sel = t >> 6, idx = t & 63;
        int n = idx >> 2, ch8 = (idx & 3) * 8;
        const unsigned short* src = &qkbuf[sel][n * 36 + ch8];
        uint2 a = *(const uint2*)src;
        uint2 c = *(const uint2*)(src + 4);
        unsigned short* dst = (sel ? kT : qT) + ((size_t)b * N_DIM + n0 + n) * CQK + ch8;
        uint4 st; st.x = a.x; st.y = a.y; st.z = c.x; st.w = c.y;
        *(uint4*)dst = st;
    }
    {
        // V store, tiled: [b][cs=t>>6][jt=n0>>5][c'=t&63][j'=n0&31 .. +16]
        const unsigned short* src = &vbb[t * 20];
        uint2 a = *(const uint2*)(src + 0);
        uint2 bq = *(const uint2*)(src + 4);
        uint2 c = *(const uint2*)(src + 8);
        uint2 d = *(const uint2*)(src + 12);
        unsigned short* dst = vbf +
            ((((size_t)(b * 4 + (t >> 6)) * 128 + (n0 >> 5)) * 64 + (t & 63)) * 32
             + (n0 & 31));
        uint4 s0; s0.x = a.x; s0.y = a.y; s0.z = bq.x; s0.w = bq.y;
        uint4 s1; s1.x = c.x; s1.y = c.y; s1.z = d.x; s1.w = d.y;
        *(uint4*)dst = s0;
        *(uint4*)(dst + 8) = s1;
    }
}

// ---------------------------------------------------------------------------
// Kernel 2: MFMA flash attention.
// R3: i-tile 64 -> 128 to HALVE total load bytes (395 MB -> 198 MB) — R1/R2
// established the kernel is load-path-bound at ~10 TB/s effective; bytes/
// output scale as 1/i-tile. To keep 2 waves/SIMD at the halved grid (256
// blocks = 1 block/CU), the block goes to 8 waves (512 thr), j-split 8x512
// (16 iters/wave). P is now SINGLE-buffered per wave (8 x 10KB = 80KB LDS);
// the lost intra-wave exp||PV overlap is covered cross-wave (wave A exp on
// VALU || wave B PV on matrix pipe at 2 waves/SIMD). V(k) loads at iter top,
// consumed ~600cy later after QK+exp (in-iter prefetch); K keeps 1-iter
// prefetch. VGPR ~230, capped by __launch_bounds__(512,2).
// grid: b(2) x qt(32) x cs(4) = 256 blocks, 512 threads.
// ---------------------------------------------------------------------------
__global__ __launch_bounds__(512, 2) void attn_kernel(
    const unsigned short* __restrict__ qT, const unsigned short* __restrict__ kT,
    const unsigned short* __restrict__ vbf, const float* __restrict__ x,
    const float* __restrict__ gamma, float* __restrict__ out)
{
    // P: 8 waves x 1 buf x [128 i][stride 40] bf16 = 81920B.
    // obuf overlays P after the loop ([64 c][132] f32 = 33792B).
    // lbuf: [8][128] partial l + [128] linv = 4608B.
    __shared__ __align__(16) char smem[81920 + 4608];
    unsigned short* pbase = (unsigned short*)smem;
    float* obuf = (float*)smem;
    float* lbuf = (float*)(smem + 81920);

    const int t  = threadIdx.x;
    const int b  = blockIdx.x >> 7;
    const int qt = (blockIdx.x >> 2) & 31;
    const int cs = blockIdx.x & 3;
    const int i0 = qt * 128;
    const int w = t >> 6, lid = t & 63, lr = lid & 15, lq = lid >> 4;

    const unsigned short* qTb = qT + (size_t)b * N_DIM * CQK;
    const unsigned short* kTb = kT + (size_t)b * N_DIM * CQK;
    // tiled V base for this (b, cs): 128 tiles x 2048 shorts
    const unsigned short* vtb = vbf + (size_t)(b * 4 + cs) * 128 * 2048;

    unsigned short* pW = pbase + w * (128 * 40);

    bf16x8 bq[8];
    #pragma unroll
    for (int it = 0; it < 8; ++it)
        bq[it] = *(const bf16x8*)&qTb[(i0 + it * 16 + lr) * CQK + lq * 8];

    f32x4 oa[4][8] = {};   // [ct][it]
    float lp[8] = {};

    const int jwbase = w * 512;           // 16 iters of 32 j
    const int vlane = lr * 32 + lq * 8;   // lane offset within a 64x32 V tile

    // prologue: K(0)
    bf16x8 akc0 = *(const bf16x8*)&kTb[(jwbase + lr) * CQK + lq * 8];
    bf16x8 akc1 = *(const bf16x8*)&kTb[(jwbase + 16 + lr) * CQK + lq * 8];

    for (int k = 0; k < 16; ++k) {
        // V(k): consumed by PV at the bottom of this iter (~600cy away)
        const unsigned short* vtk = vtb + (size_t)(w * 16 + k) * 2048;
        bf16x8 avU[4];
        #pragma unroll
        for (int ct = 0; ct < 4; ++ct)
            avU[ct] = *(const bf16x8*)&vtk[ct * 512 + vlane];
        // K(k+1) prefetch (wraps at the end; result discarded)
        const int jn = jwbase + ((k + 1) & 15) * 32;
        bf16x8 akn0 = *(const bf16x8*)&kTb[(jn + lr) * CQK + lq * 8];
        bf16x8 akn1 = *(const bf16x8*)&kTb[(jn + 16 + lr) * CQK + lq * 8];
        // QK + exp + pack + write P, fused per-it to bound transient regs
        const f32x4 z = {};
        #pragma unroll
        for (int it = 0; it < 8; ++it) {
            f32x4 s0 = MFMA(akc0, bq[it], z);
            f32x4 s1 = MFMA(akc1, bq[it], z);
            float e0 = EXP2(s0[0]), e1 = EXP2(s0[1]), e2 = EXP2(s0[2]), e3 = EXP2(s0[3]);
            float f0 = EXP2(s1[0]), f1 = EXP2(s1[1]), f2 = EXP2(s1[2]), f3 = EXP2(s1[3]);
            lp[it] += ((e0 + e1) + (e2 + e3)) + ((f0 + f1) + (f2 + f3));
            uint2 pw0; pw0.x = pk2t(e0, e1); pw0.y = pk2t(e2, e3);
            uint2 pw1; pw1.x = pk2t(f0, f1); pw1.y = pk2t(f2, f3);
            unsigned short* prow = pW + (it * 16 + lr) * 40;
            *(uint2*)&prow[lq * 4]      = pw0;
            *(uint2*)&prow[16 + lq * 4] = pw1;
        }
        // PV(k): read own P back (wave-private, no barrier)
        #pragma unroll
        for (int it = 0; it < 8; ++it) {
            bf16x8 bp = *(const bf16x8*)&pW[(it * 16 + lr) * 40 + lq * 8];
            #pragma unroll
            for (int ct = 0; ct < 4; ++ct)
                oa[ct][it] = MFMA(avU[ct], bp, oa[ct][it]);
        }
        akc0 = akn0; akc1 = akn1;
    }

    // ---- l: reduce across lq within wave ----
    #pragma unroll
    for (int it = 0; it < 8; ++it) {
        lp[it] += __shfl_xor(lp[it], 16);
        lp[it] += __shfl_xor(lp[it], 32);
    }
    if (lq == 0) {
        #pragma unroll
        for (int it = 0; it < 8; ++it)
            lbuf[w * 128 + it * 16 + lr] = lp[it];
    }
    __syncthreads();   // all waves done; P regions dead -> obuf overlay ok

    // ---- sequential cross-wave O accumulate into obuf[c][i] ----
    for (int ph = 0; ph < 8; ++ph) {
        if (w == ph) {
            #pragma unroll
            for (int ct = 0; ct < 4; ++ct)
                #pragma unroll
                for (int it = 0; it < 8; ++it)
                    #pragma unroll
                    for (int r = 0; r < 4; ++r) {
                        int addr = (ct * 16 + lq * 4 + r) * 132 + it * 16 + lr;
                        if (ph == 0) obuf[addr]  = oa[ct][it][r];
                        else         obuf[addr] += oa[ct][it][r];
                    }
        }
        __syncthreads();
    }
    if (t < 128) {
        float l = lbuf[t];
        #pragma unroll
        for (int ww = 1; ww < 8; ++ww) l += lbuf[ww * 128 + t];
        lbuf[1024 + t] = 1.f / l;
    }
    __syncthreads();

    // ---- epilogue: out = gamma*O/l + x ----
    const float g = gamma[0];
    const int c0 = cs * 64;
    const int cc = t >> 3;
    const int ic = (t & 7) * 16;
    const size_t rowbase = ((size_t)b * C_DIM + c0 + cc) * N_DIM + i0 + ic;
    #pragma unroll
    for (int k = 0; k < 4; ++k) {
        float4 ov4 = *(const float4*)&obuf[cc * 132 + ic + k * 4];
        float4 li  = *(const float4*)&lbuf[1024 + ic + k * 4];
        float4 xv  = *(const float4*)(x + rowbase + k * 4);
        float4 ov;
        ov.x = g * ov4.x * li.x + xv.x;
        ov.y = g * ov4.y * li.y + xv.y;
        ov.z = g * ov4.z * li.z + xv.z;
        ov.w = g * ov4.w * li.w + xv.w;
        *(float4*)(out + rowbase + k * 4) = ov;
    }
}

extern "C" void kernel_launch(void* const* d_in, const int* in_sizes, int n_in,
                              void* d_out, int out_size, void* d_ws, size_t ws_size,
                              hipStream_t stream) {
    const float* x     = (const float*)d_in[0];
    const float* q_w   = (const float*)d_in[1];
    const float* q_b   = (const float*)d_in[2];
    const float* k_w   = (const float*)d_in[3];
    const float* k_b   = (const float*)d_in[4];
    const float* v_w   = (const float*)d_in[5];
    const float* v_b   = (const float*)d_in[6];
    const float* gamma = (const float*)d_in[7];
    float* out = (float*)d_out;

    char* ws = (char*)d_ws;
    unsigned short* qT    = (unsigned short*)(ws);             // 512KB
    unsigned short* kT    = (unsigned short*)(ws + 524288);    // 512KB
    unsigned short* vbf   = (unsigned short*)(ws + 1048576);   // 4MB (tiled)
    unsigned short* wbf   = (unsigned short*)(ws + 5242880);   // 160KB
    float*          biasf = (float*)(ws + 5406720);            // 1.25KB

    hipLaunchKernelGGL(wconv, dim3(320), dim3(256), 0, stream,
                       q_w, q_b, k_w, k_b, v_w, v_b, wbf, biasf);
    hipLaunchKernelGGL(qkv_proj, dim3(B_DIM * 256), dim3(256), 0, stream,
                       x, wbf, biasf, qT, kT, vbf);
    hipLaunchKernelGGL(attn_kernel, dim3(B_DIM * 32 * 4), dim3(512), 0, stream,
                       qT, kT, vbf, x, gamma, out);
}

// Round 4
// 123.286 us; speedup vs baseline: 1.4440x; 1.4440x over previous
//
#include <hip/hip_runtime.h>

#define C_DIM 256
#define CQK   32
#define N_DIM 4096
#define B_DIM 2

typedef __attribute__((ext_vector_type(8))) short bf16x8;
typedef __attribute__((ext_vector_type(4))) float f32x4;

__device__ __forceinline__ unsigned short f2bf(float f) {
    union { float f; unsigned u; } v; v.f = f;
    unsigned r = v.u + 0x7FFFu + ((v.u >> 16) & 1u);   // RNE
    return (unsigned short)(r >> 16);
}
__device__ __forceinline__ unsigned pk2(float a, float b) {
    return (unsigned)f2bf(a) | ((unsigned)f2bf(b) << 16);
}
// truncating pack via v_perm_b32 (1 VALU op): low16 = bf16_trunc(a), high = b
__device__ __forceinline__ unsigned pk2t(float a, float b) {
    union { float f; unsigned u; } ua, ub; ua.f = a; ub.f = b;
    return __builtin_amdgcn_perm(ub.u, ua.u, 0x07060302u);
}
#define EXP2(x) __builtin_amdgcn_exp2f(x)
#define MFMA(A, B, C) __builtin_amdgcn_mfma_f32_16x16x32_bf16((A), (B), (C), 0, 0, 0)

// ---------------------------------------------------------------------------
// Kernel 0: convert W (q|k|v rows, 320x256) to bf16 + gather biases.
// q rows (and q bias) pre-scaled by log2(e) so attn uses raw 2^x.
// ---------------------------------------------------------------------------
__global__ __launch_bounds__(256) void wconv(
    const float* __restrict__ q_w, const float* __restrict__ q_b,
    const float* __restrict__ k_w, const float* __restrict__ k_b,
    const float* __restrict__ v_w, const float* __restrict__ v_b,
    unsigned short* __restrict__ wbf, float* __restrict__ biasf)
{
    const float LOG2E = 1.4426950408889634f;
    int o = blockIdx.x, c = threadIdx.x;
    float w;
    if (o < 32)       w = q_w[o * C_DIM + c] * LOG2E;
    else if (o < 64)  w = k_w[(o - 32) * C_DIM + c];
    else              w = v_w[(o - 64) * C_DIM + c];
    wbf[o * C_DIM + c] = f2bf(w);
    if (c == 0) biasf[o] = (o < 32) ? q_b[o] * LOG2E
                         : (o < 64) ? k_b[o - 32] : v_b[o - 64];
}

// ---------------------------------------------------------------------------
// Kernel 1: QKV projection via MFMA, 16-col n-tiles.
// V stored TILED as [b][cs(4)][jt(128)][c'(64)][j'(32)] bf16 — the exact 4KB
// tile one attn wave consumes per iteration (full-128B-line loads, proven R2).
// ---------------------------------------------------------------------------
__global__ __launch_bounds__(256, 2) void qkv_proj(
    const float* __restrict__ x, const unsigned short* __restrict__ wbf,
    const float* __restrict__ biasf,
    unsigned short* __restrict__ qT, unsigned short* __restrict__ kT,
    unsigned short* __restrict__ vbf)
{
    __shared__ __align__(16) unsigned short xsT[16 * 264];     // [n][c] bf16
    __shared__ __align__(16) unsigned short qkbuf[2][16 * 36]; // q/k bounce
    __shared__ __align__(16) unsigned short vbb[256 * 20];     // v bounce, stride 20
    const int t  = threadIdx.x;
    const int b  = blockIdx.x >> 8;
    const int n0 = (blockIdx.x & 255) * 16;

    {
        int n4 = t & 3, cq = t >> 2;   // cq 0..63
        const float* xp = x + ((size_t)(b * C_DIM + cq * 4)) * N_DIM + n0 + n4 * 4;
        float4 r0 = *(const float4*)xp;
        float4 r1 = *(const float4*)(xp + N_DIM);
        float4 r2 = *(const float4*)(xp + 2 * N_DIM);
        float4 r3 = *(const float4*)(xp + 3 * N_DIM);
        float a0[4], a1[4], a2[4], a3[4];
        *(float4*)a0 = r0; *(float4*)a1 = r1; *(float4*)a2 = r2; *(float4*)a3 = r3;
        #pragma unroll
        for (int k = 0; k < 4; ++k) {
            uint2 pw;
            pw.x = pk2(a0[k], a1[k]);
            pw.y = pk2(a2[k], a3[k]);
            *(uint2*)&xsT[(n4 * 4 + k) * 264 + cq * 4] = pw;
        }
    }
    __syncthreads();

    const int w = t >> 6, lid = t & 63, lr = lid & 15, lq = lid >> 4;
    f32x4 acc[5] = {};
    #pragma unroll
    for (int ks = 0; ks < 8; ++ks) {
        bf16x8 xb = *(const bf16x8*)&xsT[lr * 264 + ks * 32 + lq * 8];
        #pragma unroll
        for (int u = 0; u < 5; ++u) {
            int gm = w * 5 + u;
            bf16x8 af = *(const bf16x8*)&wbf[(gm * 16 + lr) * C_DIM + ks * 32 + lq * 8];
            acc[u] = MFMA(af, xb, acc[u]);
        }
    }
    #pragma unroll
    for (int u = 0; u < 5; ++u) {
        int gm = w * 5 + u;
        float bv[4];
        *(float4*)bv = *(const float4*)&biasf[gm * 16 + lq * 4];
        if (gm >= 4) {
            int vc = (gm - 4) * 16 + lq * 4;
            #pragma unroll
            for (int r = 0; r < 4; ++r)
                vbb[(vc + r) * 20 + lr] = f2bf(acc[u][r] + bv[r]);
        } else {
            int sel = gm >> 1, half = gm & 1;   // wave 0 only
            uint2 pw;
            pw.x = pk2(acc[u][0] + bv[0], acc[u][1] + bv[1]);
            pw.y = pk2(acc[u][2] + bv[2], acc[u][3] + bv[3]);
            *(uint2*)&qkbuf[sel][lr * 36 + half * 16 + lq * 4] = pw;
        }
    }
    __syncthreads();
    if (t < 128) {
        int sel = t >> 6, idx = t & 63;
        int n = idx >> 2, ch8 = (idx & 3) * 8;
        const unsigned short* src = &qkbuf[sel][n * 36 + ch8];
        uint2 a = *(const uint2*)src;
        uint2 c = *(const uint2*)(src + 4);
        unsigned short* dst = (sel ? kT : qT) + ((size_t)b * N_DIM + n0 + n) * CQK + ch8;
        uint4 st; st.x = a.x; st.y = a.y; st.z = c.x; st.w = c.y;
        *(uint4*)dst = st;
    }
    {
        // V store, tiled: [b][cs=t>>6][jt=n0>>5][c'=t&63][j'=n0&31 .. +16]
        const unsigned short* src = &vbb[t * 20];
        uint2 a = *(const uint2*)(src + 0);
        uint2 bq = *(const uint2*)(src + 4);
        uint2 c = *(const uint2*)(src + 8);
        uint2 d = *(const uint2*)(src + 12);
        unsigned short* dst = vbf +
            ((((size_t)(b * 4 + (t >> 6)) * 128 + (n0 >> 5)) * 64 + (t & 63)) * 32
             + (n0 & 31));
        uint4 s0; s0.x = a.x; s0.y = a.y; s0.z = bq.x; s0.w = bq.y;
        uint4 s1; s1.x = c.x; s1.y = c.y; s1.z = d.x; s1.w = d.y;
        *(uint4*)dst = s0;
        *(uint4*)(dst + 8) = s1;
    }
}

// ---------------------------------------------------------------------------
// Kernel 2: MFMA flash attention — R2's proven structure (j-split across 4
// waves, barrier-free, double-buffered wave-private P; attn ~40us) with ONE
// change: XCD-AWARE GROUP DECODE. There are exactly 8 (b,cs) groups, each
// with a ~1MB shared working set (K 256KB + V-slice 512KB + Q 256KB), and 8
// XCDs with 4MB private L2s. Old decode (cs fastest) spread every group
// across all XCDs -> each L2 tried to hold ~8MB -> thrash -> the measured
// ~10 TB/s load wall (R1: rate invariant to wave count => bandwidth wall;
// FETCH_SIZE ~11.5MB => working set served from beyond L2). New decode:
// group = blockIdx & 7, so with round-robin workgroup->XCD dispatch
// (XCD = wgid % 8, the T1-swizzle assumption) each XCD owns ONE group:
// 64 blocks reusing a 1MB L2-resident set. 64 blocks/XCD = 2/CU, balanced.
// grid: 512 blocks = 8 groups x 64 qt, 256 threads (4 waves x 1024 j).
// ---------------------------------------------------------------------------
__global__ __launch_bounds__(256, 2) void attn_kernel(
    const unsigned short* __restrict__ qT, const unsigned short* __restrict__ kT,
    const unsigned short* __restrict__ vbf, const float* __restrict__ x,
    const float* __restrict__ gamma, float* __restrict__ out)
{
    // P: 4 waves x 2 bufs x [64 i][stride 40] bf16 = 40960B.
    // obuf overlays P after the loop ([64 c][68] f32 = 17408B).
    // lbuf: [4][64] partial l + [64] linv = 1280B.
    __shared__ __align__(16) char smem[40960 + 1536];
    unsigned short* pbase = (unsigned short*)smem;
    float* obuf = (float*)smem;
    float* lbuf = (float*)(smem + 40960);

    const int t  = threadIdx.x;
    // XCD-aware decode: group (b,cs) = blockIdx & 7 -> one group per XCD.
    const int g  = blockIdx.x & 7;
    const int qt = blockIdx.x >> 3;     // 0..63
    const int b  = g >> 2;
    const int cs = g & 3;
    const int i0 = qt * 64;
    const int w = t >> 6, lid = t & 63, lr = lid & 15, lq = lid >> 4;

    const unsigned short* qTb = qT + (size_t)b * N_DIM * CQK;
    const unsigned short* kTb = kT + (size_t)b * N_DIM * CQK;
    // tiled V base for this (b, cs): 128 tiles x 2048 shorts
    const unsigned short* vtb = vbf + (size_t)(b * 4 + cs) * 128 * 2048;

    unsigned short* pW0 = pbase + (w * 2 + 0) * (64 * 40);
    unsigned short* pW1 = pbase + (w * 2 + 1) * (64 * 40);

    bf16x8 bq[4];
    #pragma unroll
    for (int it = 0; it < 4; ++it)
        bq[it] = *(const bf16x8*)&qTb[(i0 + it * 16 + lr) * CQK + lq * 8];

    f32x4 oa[4][4] = {};   // [ct][it]
    float lp[4] = {};

    const int jwbase = w * 1024;   // 32 iters of 32 j
    const int vlane = lr * 32 + lq * 8;   // lane offset within a 64x32 V tile

    // prologue: K(0)
    bf16x8 akc0 = *(const bf16x8*)&kTb[(jwbase + lr) * CQK + lq * 8];
    bf16x8 akc1 = *(const bf16x8*)&kTb[(jwbase + 16 + lr) * CQK + lq * 8];
    bf16x8 avU[4];   // V(k-1), consumed by PV at iter k

    // ---- peeled iter 0: S(0)+exp -> P(0) in pW0; issue V(0), K(1) ----
    {
        const unsigned short* vt0 = vtb + (size_t)(w * 32) * 2048;
        #pragma unroll
        for (int ct = 0; ct < 4; ++ct)
            avU[ct] = *(const bf16x8*)&vt0[ct * 512 + vlane];
        bf16x8 akn0 = *(const bf16x8*)&kTb[(jwbase + 32 + lr) * CQK + lq * 8];
        bf16x8 akn1 = *(const bf16x8*)&kTb[(jwbase + 32 + 16 + lr) * CQK + lq * 8];
        const f32x4 z = {};
        #pragma unroll
        for (int it = 0; it < 4; ++it) {
            f32x4 s0 = MFMA(akc0, bq[it], z);
            f32x4 s1 = MFMA(akc1, bq[it], z);
            float e0 = EXP2(s0[0]), e1 = EXP2(s0[1]), e2 = EXP2(s0[2]), e3 = EXP2(s0[3]);
            float f0 = EXP2(s1[0]), f1 = EXP2(s1[1]), f2 = EXP2(s1[2]), f3 = EXP2(s1[3]);
            lp[it] += ((e0 + e1) + (e2 + e3)) + ((f0 + f1) + (f2 + f3));
            uint2 pw0; pw0.x = pk2t(e0, e1); pw0.y = pk2t(e2, e3);
            uint2 pw1; pw1.x = pk2t(f0, f1); pw1.y = pk2t(f2, f3);
            unsigned short* prow = pW0 + (it * 16 + lr) * 40;
            *(uint2*)&prow[lq * 4]      = pw0;
            *(uint2*)&prow[16 + lq * 4] = pw1;
        }
        akc0 = akn0; akc1 = akn1;
    }

    // ---- steady state k = 1..31 ----
    #pragma unroll 2
    for (int k = 1; k < 32; ++k) {
        const int jn = jwbase + ((k + 1) & 31) * 32;
        // V(k) in flight (consumed by PV at iter k+1 / drain) — contiguous tile
        const unsigned short* vtk = vtb + (size_t)(w * 32 + k) * 2048;
        bf16x8 avI[4];
        #pragma unroll
        for (int ct = 0; ct < 4; ++ct)
            avI[ct] = *(const bf16x8*)&vtk[ct * 512 + vlane];
        // K(k+1) in flight
        bf16x8 akn0 = *(const bf16x8*)&kTb[(jn + lr) * CQK + lq * 8];
        bf16x8 akn1 = *(const bf16x8*)&kTb[(jn + 16 + lr) * CQK + lq * 8];
        // P(k-1) reads from buf[(k-1)&1] — no dependency on this iter's work
        const unsigned short* pR = (k & 1) ? pW0 : pW1;
        bf16x8 bp[4];
        #pragma unroll
        for (int it = 0; it < 4; ++it)
            bp[it] = *(const bf16x8*)&pR[(it * 16 + lr) * 40 + lq * 8];
        // S(k)
        const f32x4 z = {};
        f32x4 s[4][2];
        #pragma unroll
        for (int it = 0; it < 4; ++it) {
            s[it][0] = MFMA(akc0, bq[it], z);
            s[it][1] = MFMA(akc1, bq[it], z);
        }
        // PV(k-1): overlaps the exp/pack below via matrix-vs-trans pipes
        #pragma unroll
        for (int it = 0; it < 4; ++it)
            #pragma unroll
            for (int ct = 0; ct < 4; ++ct)
                oa[ct][it] = MFMA(avU[ct], bp[it], oa[ct][it]);
        // exp + pack + write P(k) to buf[k&1]
        unsigned short* pWc = (k & 1) ? pW1 : pW0;
        #pragma unroll
        for (int it = 0; it < 4; ++it) {
            float e0 = EXP2(s[it][0][0]), e1 = EXP2(s[it][0][1]);
            float e2 = EXP2(s[it][0][2]), e3 = EXP2(s[it][0][3]);
            float f0 = EXP2(s[it][1][0]), f1 = EXP2(s[it][1][1]);
            float f2 = EXP2(s[it][1][2]), f3 = EXP2(s[it][1][3]);
            lp[it] += ((e0 + e1) + (e2 + e3)) + ((f0 + f1) + (f2 + f3));
            uint2 pw0; pw0.x = pk2t(e0, e1); pw0.y = pk2t(e2, e3);
            uint2 pw1; pw1.x = pk2t(f0, f1); pw1.y = pk2t(f2, f3);
            unsigned short* prow = pWc + (it * 16 + lr) * 40;
            *(uint2*)&prow[lq * 4]      = pw0;
            *(uint2*)&prow[16 + lq * 4] = pw1;
        }
        // rotate
        akc0 = akn0; akc1 = akn1;
        #pragma unroll
        for (int ct = 0; ct < 4; ++ct) avU[ct] = avI[ct];
    }

    // ---- drain: PV(31), P(31) in pW1 ----
    {
        bf16x8 bp[4];
        #pragma unroll
        for (int it = 0; it < 4; ++it)
            bp[it] = *(const bf16x8*)&pW1[(it * 16 + lr) * 40 + lq * 8];
        #pragma unroll
        for (int it = 0; it < 4; ++it)
            #pragma unroll
            for (int ct = 0; ct < 4; ++ct)
                oa[ct][it] = MFMA(avU[ct], bp[it], oa[ct][it]);
    }

    // ---- l: reduce across lq within wave ----
    #pragma unroll
    for (int it = 0; it < 4; ++it) {
        lp[it] += __shfl_xor(lp[it], 16);
        lp[it] += __shfl_xor(lp[it], 32);
    }
    if (lq == 0) {
        #pragma unroll
        for (int it = 0; it < 4; ++it)
            lbuf[w * 64 + it * 16 + lr] = lp[it];
    }
    __syncthreads();   // all waves done; P regions dead -> obuf overlay ok

    // ---- sequential cross-wave O accumulate into obuf[c][i] ----
    for (int ph = 0; ph < 4; ++ph) {
        if (w == ph) {
            #pragma unroll
            for (int ct = 0; ct < 4; ++ct)
                #pragma unroll
                for (int it = 0; it < 4; ++it)
                    #pragma unroll
                    for (int r = 0; r < 4; ++r) {
                        int addr = (ct * 16 + lq * 4 + r) * 68 + it * 16 + lr;
                        if (ph == 0) obuf[addr]  = oa[ct][it][r];
                        else         obuf[addr] += oa[ct][it][r];
                    }
        }
        __syncthreads();
    }
    if (t < 64) {
        float l = lbuf[t] + lbuf[64 + t] + lbuf[128 + t] + lbuf[192 + t];
        lbuf[256 + t] = 1.f / l;
    }
    __syncthreads();

    // ---- epilogue: out = gamma*O/l + x ----
    const float g2 = gamma[0];
    const int c0 = cs * 64;
    const int cc = t >> 2;
    const int ic = (t & 3) * 16;
    const size_t rowbase = ((size_t)b * C_DIM + c0 + cc) * N_DIM + i0 + ic;
    #pragma unroll
    for (int k = 0; k < 4; ++k) {
        float4 ov4 = *(const float4*)&obuf[cc * 68 + ic + k * 4];
        float4 li  = *(const float4*)&lbuf[256 + ic + k * 4];
        float4 xv  = *(const float4*)(x + rowbase + k * 4);
        float4 ov;
        ov.x = g2 * ov4.x * li.x + xv.x;
        ov.y = g2 * ov4.y * li.y + xv.y;
        ov.z = g2 * ov4.z * li.z + xv.z;
        ov.w = g2 * ov4.w * li.w + xv.w;
        *(float4*)(out + rowbase + k * 4) = ov;
    }
}

extern "C" void kernel_launch(void* const* d_in, const int* in_sizes, int n_in,
                              void* d_out, int out_size, void* d_ws, size_t ws_size,
                              hipStream_t stream) {
    const float* x     = (const float*)d_in[0];
    const float* q_w   = (const float*)d_in[1];
    const float* q_b   = (const float*)d_in[2];
    const float* k_w   = (const float*)d_in[3];
    const float* k_b   = (const float*)d_in[4];
    const float* v_w   = (const float*)d_in[5];
    const float* v_b   = (const float*)d_in[6];
    const float* gamma = (const float*)d_in[7];
    float* out = (float*)d_out;

    char* ws = (char*)d_ws;
    unsigned short* qT    = (unsigned short*)(ws);             // 512KB
    unsigned short* kT    = (unsigned short*)(ws + 524288);    // 512KB
    unsigned short* vbf   = (unsigned short*)(ws + 1048576);   // 4MB (tiled)
    unsigned short* wbf   = (unsigned short*)(ws + 5242880);   // 160KB
    float*          biasf = (float*)(ws + 5406720);            // 1.25KB

    hipLaunchKernelGGL(wconv, dim3(320), dim3(256), 0, stream,
                       q_w, q_b, k_w, k_b, v_w, v_b, wbf, biasf);
    hipLaunchKernelGGL(qkv_proj, dim3(B_DIM * 256), dim3(256), 0, stream,
                       x, wbf, biasf, qT, kT, vbf);
    hipLaunchKernelGGL(attn_kernel, dim3(B_DIM * 64 * 4), dim3(256), 0, stream,
                       qT, kT, vbf, x, gamma, out);
}

// Round 5
// 120.380 us; speedup vs baseline: 1.4788x; 1.0241x over previous
//
#include <hip/hip_runtime.h>

#define C_DIM 256
#define CQK   32
#define N_DIM 4096
#define B_DIM 2

typedef __attribute__((ext_vector_type(8))) short bf16x8;
typedef __attribute__((ext_vector_type(4))) float f32x4;

__device__ __forceinline__ unsigned short f2bf(float f) {
    union { float f; unsigned u; } v; v.f = f;
    unsigned r = v.u + 0x7FFFu + ((v.u >> 16) & 1u);   // RNE
    return (unsigned short)(r >> 16);
}
__device__ __forceinline__ unsigned pk2(float a, float b) {
    return (unsigned)f2bf(a) | ((unsigned)f2bf(b) << 16);
}
// truncating pack via v_perm_b32 (1 VALU op): low16 = bf16_trunc(a), high = b
__device__ __forceinline__ unsigned pk2t(float a, float b) {
    union { float f; unsigned u; } ua, ub; ua.f = a; ub.f = b;
    return __builtin_amdgcn_perm(ub.u, ua.u, 0x07060302u);
}
#define EXP2(x) __builtin_amdgcn_exp2f(x)
#define MFMA(A, B, C) __builtin_amdgcn_mfma_f32_16x16x32_bf16((A), (B), (C), 0, 0, 0)

// ---------------------------------------------------------------------------
// Kernel 0: convert W (q|k|v rows, 320x256) to bf16 + gather biases.
// q rows (and q bias) pre-scaled by log2(e) so attn uses raw 2^x.
// ---------------------------------------------------------------------------
__global__ __launch_bounds__(256) void wconv(
    const float* __restrict__ q_w, const float* __restrict__ q_b,
    const float* __restrict__ k_w, const float* __restrict__ k_b,
    const float* __restrict__ v_w, const float* __restrict__ v_b,
    unsigned short* __restrict__ wbf, float* __restrict__ biasf)
{
    const float LOG2E = 1.4426950408889634f;
    int o = blockIdx.x, c = threadIdx.x;
    float w;
    if (o < 32)       w = q_w[o * C_DIM + c] * LOG2E;
    else if (o < 64)  w = k_w[(o - 32) * C_DIM + c];
    else              w = v_w[(o - 64) * C_DIM + c];
    wbf[o * C_DIM + c] = f2bf(w);
    if (c == 0) biasf[o] = (o < 32) ? q_b[o] * LOG2E
                         : (o < 64) ? k_b[o - 32] : v_b[o - 64];
}

// ---------------------------------------------------------------------------
// Kernel 1: QKV projection via MFMA.
// R5: n-tile 16 -> 32 (512 -> 256 blocks). Rationale: every block reads the
// FULL 160KB weight matrix; 512 blocks = 80MB broadcast traffic vs a ~5MB
// qkv-out. Widening halves that to 40MB, and the weight fragment af is
// loaded ONCE per (gm,ks) and reused for both n-halves (2 MFMAs per load).
// Also: n-tile 32 = exactly one V tile -> single fully-coalesced V store.
// V stored TILED as [b][cs(4)][jt(128)][c'(64)][j'(32)] bf16 (proven R2).
// ---------------------------------------------------------------------------
__global__ __launch_bounds__(256, 2) void qkv_proj(
    const float* __restrict__ x, const unsigned short* __restrict__ wbf,
    const float* __restrict__ biasf,
    unsigned short* __restrict__ qT, unsigned short* __restrict__ kT,
    unsigned short* __restrict__ vbf)
{
    __shared__ __align__(16) unsigned short xsT[32 * 264];     // [n][c] bf16
    __shared__ __align__(16) unsigned short qkbuf[2][32 * 36]; // q/k bounce
    __shared__ __align__(16) unsigned short vbb[256 * 36];     // v bounce, stride 36
    const int t  = threadIdx.x;
    const int b  = blockIdx.x >> 7;
    const int n0 = (blockIdx.x & 127) * 32;

    {
        int n4 = t & 3, cq = t >> 2;   // cq 0..63, n-octet n4*8
        const float* xp = x + ((size_t)(b * C_DIM + cq * 4)) * N_DIM + n0 + n4 * 8;
        float a0[8], a1[8], a2[8], a3[8];
        *(float4*)(a0)     = *(const float4*)(xp);
        *(float4*)(a0 + 4) = *(const float4*)(xp + 4);
        *(float4*)(a1)     = *(const float4*)(xp + N_DIM);
        *(float4*)(a1 + 4) = *(const float4*)(xp + N_DIM + 4);
        *(float4*)(a2)     = *(const float4*)(xp + 2 * N_DIM);
        *(float4*)(a2 + 4) = *(const float4*)(xp + 2 * N_DIM + 4);
        *(float4*)(a3)     = *(const float4*)(xp + 3 * N_DIM);
        *(float4*)(a3 + 4) = *(const float4*)(xp + 3 * N_DIM + 4);
        #pragma unroll
        for (int k = 0; k < 8; ++k) {
            uint2 pw;
            pw.x = pk2(a0[k], a1[k]);
            pw.y = pk2(a2[k], a3[k]);
            *(uint2*)&xsT[(n4 * 8 + k) * 264 + cq * 4] = pw;
        }
    }
    __syncthreads();

    const int w = t >> 6, lid = t & 63, lr = lid & 15, lq = lid >> 4;
    f32x4 acc[5][2] = {};   // [u][nh]
    #pragma unroll
    for (int ks = 0; ks < 8; ++ks) {
        bf16x8 xb0 = *(const bf16x8*)&xsT[lr * 264 + ks * 32 + lq * 8];
        bf16x8 xb1 = *(const bf16x8*)&xsT[(16 + lr) * 264 + ks * 32 + lq * 8];
        #pragma unroll
        for (int u = 0; u < 5; ++u) {
            int gm = w * 5 + u;
            bf16x8 af = *(const bf16x8*)&wbf[(gm * 16 + lr) * C_DIM + ks * 32 + lq * 8];
            acc[u][0] = MFMA(af, xb0, acc[u][0]);
            acc[u][1] = MFMA(af, xb1, acc[u][1]);
        }
    }
    #pragma unroll
    for (int u = 0; u < 5; ++u) {
        int gm = w * 5 + u;
        float bv[4];
        *(float4*)bv = *(const float4*)&biasf[gm * 16 + lq * 4];
        #pragma unroll
        for (int nh = 0; nh < 2; ++nh) {
            if (gm >= 4) {
                int vc = (gm - 4) * 16 + lq * 4;
                #pragma unroll
                for (int r = 0; r < 4; ++r)
                    vbb[(vc + r) * 36 + nh * 16 + lr] = f2bf(acc[u][nh][r] + bv[r]);
            } else {
                int sel = gm >> 1, half = gm & 1;   // wave 0 only
                uint2 pw;
                pw.x = pk2(acc[u][nh][0] + bv[0], acc[u][nh][1] + bv[1]);
                pw.y = pk2(acc[u][nh][2] + bv[2], acc[u][nh][3] + bv[3]);
                *(uint2*)&qkbuf[sel][(nh * 16 + lr) * 36 + half * 16 + lq * 4] = pw;
            }
        }
    }
    __syncthreads();
    {
        // q/k out: 2 sel x 32 n x 32 ch, 256 threads = one 8-ch chunk each
        int sel = t >> 7, idx = t & 127;
        int n = idx >> 2, ch8 = (idx & 3) * 8;
        const unsigned short* src = &qkbuf[sel][n * 36 + ch8];
        uint2 a = *(const uint2*)src;
        uint2 c = *(const uint2*)(src + 4);
        unsigned short* dst = (sel ? kT : qT) + ((size_t)b * N_DIM + n0 + n) * CQK + ch8;
        uint4 st; st.x = a.x; st.y = a.y; st.z = c.x; st.w = c.y;
        *(uint4*)dst = st;
    }
    {
        // V store: n-tile 32 = exactly one tile (b, cs=t>>6, jt=n0>>5);
        // thread t writes its channel row (64B contiguous, fully coalesced)
        const unsigned short* src = &vbb[t * 36];
        uint2 a = *(const uint2*)(src + 0);
        uint2 bq = *(const uint2*)(src + 4);
        uint2 c = *(const uint2*)(src + 8);
        uint2 d = *(const uint2*)(src + 12);
        uint2 e = *(const uint2*)(src + 16);
        uint2 f = *(const uint2*)(src + 20);
        uint2 g = *(const uint2*)(src + 24);
        uint2 h = *(const uint2*)(src + 28);
        unsigned short* dst = vbf +
            (((size_t)(b * 4 + (t >> 6)) * 128 + (n0 >> 5)) * 64 + (t & 63)) * 32;
        uint4 s0; s0.x = a.x; s0.y = a.y; s0.z = bq.x; s0.w = bq.y;
        uint4 s1; s1.x = c.x; s1.y = c.y; s1.z = d.x; s1.w = d.y;
        uint4 s2; s2.x = e.x; s2.y = e.y; s2.z = f.x; s2.w = f.y;
        uint4 s3; s3.x = g.x; s3.y = g.y; s3.z = h.x; s3.w = h.y;
        *(uint4*)(dst)      = s0;
        *(uint4*)(dst + 8)  = s1;
        *(uint4*)(dst + 16) = s2;
        *(uint4*)(dst + 24) = s3;
    }
}

// ---------------------------------------------------------------------------
// Kernel 2: MFMA flash attention — R2's proven structure and decode (j-split
// across 4 waves, barrier-free, double-buffered wave-private P; attn ~40us
// in-situ). R5 reverts R4's XCD group decode: the cross-round ledger showed
// it <=neutral in-situ and the cold-profile (77.8us vs R0's 50.4) suggests
// it can hurt if workgroup->XCD assignment is chunked rather than
// round-robin — the natural order already gives contiguous chunks a
// 2.4MB L2-fit working set.
// grid: b(2) x qt(64) x cs(4) = 512 blocks, 256 threads (4 waves x 1024 j).
// ---------------------------------------------------------------------------
__global__ __launch_bounds__(256, 2) void attn_kernel(
    const unsigned short* __restrict__ qT, const unsigned short* __restrict__ kT,
    const unsigned short* __restrict__ vbf, const float* __restrict__ x,
    const float* __restrict__ gamma, float* __restrict__ out)
{
    // P: 4 waves x 2 bufs x [64 i][stride 40] bf16 = 40960B.
    // obuf overlays P after the loop ([64 c][68] f32 = 17408B).
    // lbuf: [4][64] partial l + [64] linv = 1280B.
    __shared__ __align__(16) char smem[40960 + 1536];
    unsigned short* pbase = (unsigned short*)smem;
    float* obuf = (float*)smem;
    float* lbuf = (float*)(smem + 40960);

    const int t  = threadIdx.x;
    const int b  = blockIdx.x >> 8;
    const int qt = (blockIdx.x >> 2) & 63;
    const int cs = blockIdx.x & 3;
    const int i0 = qt * 64;
    const int w = t >> 6, lid = t & 63, lr = lid & 15, lq = lid >> 4;

    const unsigned short* qTb = qT + (size_t)b * N_DIM * CQK;
    const unsigned short* kTb = kT + (size_t)b * N_DIM * CQK;
    // tiled V base for this (b, cs): 128 tiles x 2048 shorts
    const unsigned short* vtb = vbf + (size_t)(b * 4 + cs) * 128 * 2048;

    unsigned short* pW0 = pbase + (w * 2 + 0) * (64 * 40);
    unsigned short* pW1 = pbase + (w * 2 + 1) * (64 * 40);

    bf16x8 bq[4];
    #pragma unroll
    for (int it = 0; it < 4; ++it)
        bq[it] = *(const bf16x8*)&qTb[(i0 + it * 16 + lr) * CQK + lq * 8];

    f32x4 oa[4][4] = {};   // [ct][it]
    float lp[4] = {};

    const int jwbase = w * 1024;   // 32 iters of 32 j
    const int vlane = lr * 32 + lq * 8;   // lane offset within a 64x32 V tile

    // prologue: K(0)
    bf16x8 akc0 = *(const bf16x8*)&kTb[(jwbase + lr) * CQK + lq * 8];
    bf16x8 akc1 = *(const bf16x8*)&kTb[(jwbase + 16 + lr) * CQK + lq * 8];
    bf16x8 avU[4];   // V(k-1), consumed by PV at iter k

    // ---- peeled iter 0: S(0)+exp -> P(0) in pW0; issue V(0), K(1) ----
    {
        const unsigned short* vt0 = vtb + (size_t)(w * 32) * 2048;
        #pragma unroll
        for (int ct = 0; ct < 4; ++ct)
            avU[ct] = *(const bf16x8*)&vt0[ct * 512 + vlane];
        bf16x8 akn0 = *(const bf16x8*)&kTb[(jwbase + 32 + lr) * CQK + lq * 8];
        bf16x8 akn1 = *(const bf16x8*)&kTb[(jwbase + 32 + 16 + lr) * CQK + lq * 8];
        const f32x4 z = {};
        #pragma unroll
        for (int it = 0; it < 4; ++it) {
            f32x4 s0 = MFMA(akc0, bq[it], z);
            f32x4 s1 = MFMA(akc1, bq[it], z);
            float e0 = EXP2(s0[0]), e1 = EXP2(s0[1]), e2 = EXP2(s0[2]), e3 = EXP2(s0[3]);
            float f0 = EXP2(s1[0]), f1 = EXP2(s1[1]), f2 = EXP2(s1[2]), f3 = EXP2(s1[3]);
            lp[it] += ((e0 + e1) + (e2 + e3)) + ((f0 + f1) + (f2 + f3));
            uint2 pw0; pw0.x = pk2t(e0, e1); pw0.y = pk2t(e2, e3);
            uint2 pw1; pw1.x = pk2t(f0, f1); pw1.y = pk2t(f2, f3);
            unsigned short* prow = pW0 + (it * 16 + lr) * 40;
            *(uint2*)&prow[lq * 4]      = pw0;
            *(uint2*)&prow[16 + lq * 4] = pw1;
        }
        akc0 = akn0; akc1 = akn1;
    }

    // ---- steady state k = 1..31 ----
    #pragma unroll 2
    for (int k = 1; k < 32; ++k) {
        const int jn = jwbase + ((k + 1) & 31) * 32;
        // V(k) in flight (consumed by PV at iter k+1 / drain) — contiguous tile
        const unsigned short* vtk = vtb + (size_t)(w * 32 + k) * 2048;
        bf16x8 avI[4];
        #pragma unroll
        for (int ct = 0; ct < 4; ++ct)
            avI[ct] = *(const bf16x8*)&vtk[ct * 512 + vlane];
        // K(k+1) in flight
        bf16x8 akn0 = *(const bf16x8*)&kTb[(jn + lr) * CQK + lq * 8];
        bf16x8 akn1 = *(const bf16x8*)&kTb[(jn + 16 + lr) * CQK + lq * 8];
        // P(k-1) reads from buf[(k-1)&1] — no dependency on this iter's work
        const unsigned short* pR = (k & 1) ? pW0 : pW1;
        bf16x8 bp[4];
        #pragma unroll
        for (int it = 0; it < 4; ++it)
            bp[it] = *(const bf16x8*)&pR[(it * 16 + lr) * 40 + lq * 8];
        // S(k)
        const f32x4 z = {};
        f32x4 s[4][2];
        #pragma unroll
        for (int it = 0; it < 4; ++it) {
            s[it][0] = MFMA(akc0, bq[it], z);
            s[it][1] = MFMA(akc1, bq[it], z);
        }
        // PV(k-1): overlaps the exp/pack below via matrix-vs-trans pipes
        #pragma unroll
        for (int it = 0; it < 4; ++it)
            #pragma unroll
            for (int ct = 0; ct < 4; ++ct)
                oa[ct][it] = MFMA(avU[ct], bp[it], oa[ct][it]);
        // exp + pack + write P(k) to buf[k&1]
        unsigned short* pWc = (k & 1) ? pW1 : pW0;
        #pragma unroll
        for (int it = 0; it < 4; ++it) {
            float e0 = EXP2(s[it][0][0]), e1 = EXP2(s[it][0][1]);
            float e2 = EXP2(s[it][0][2]), e3 = EXP2(s[it][0][3]);
            float f0 = EXP2(s[it][1][0]), f1 = EXP2(s[it][1][1]);
            float f2 = EXP2(s[it][1][2]), f3 = EXP2(s[it][1][3]);
            lp[it] += ((e0 + e1) + (e2 + e3)) + ((f0 + f1) + (f2 + f3));
            uint2 pw0; pw0.x = pk2t(e0, e1); pw0.y = pk2t(e2, e3);
            uint2 pw1; pw1.x = pk2t(f0, f1); pw1.y = pk2t(f2, f3);
            unsigned short* prow = pWc + (it * 16 + lr) * 40;
            *(uint2*)&prow[lq * 4]      = pw0;
            *(uint2*)&prow[16 + lq * 4] = pw1;
        }
        // rotate
        akc0 = akn0; akc1 = akn1;
        #pragma unroll
        for (int ct = 0; ct < 4; ++ct) avU[ct] = avI[ct];
    }

    // ---- drain: PV(31), P(31) in pW1 ----
    {
        bf16x8 bp[4];
        #pragma unroll
        for (int it = 0; it < 4; ++it)
            bp[it] = *(const bf16x8*)&pW1[(it * 16 + lr) * 40 + lq * 8];
        #pragma unroll
        for (int it = 0; it < 4; ++it)
            #pragma unroll
            for (int ct = 0; ct < 4; ++ct)
                oa[ct][it] = MFMA(avU[ct], bp[it], oa[ct][it]);
    }

    // ---- l: reduce across lq within wave ----
    #pragma unroll
    for (int it = 0; it < 4; ++it) {
        lp[it] += __shfl_xor(lp[it], 16);
        lp[it] += __shfl_xor(lp[it], 32);
    }
    if (lq == 0) {
        #pragma unroll
        for (int it = 0; it < 4; ++it)
            lbuf[w * 64 + it * 16 + lr] = lp[it];
    }
    __syncthreads();   // all waves done; P regions dead -> obuf overlay ok

    // ---- sequential cross-wave O accumulate into obuf[c][i] ----
    for (int ph = 0; ph < 4; ++ph) {
        if (w == ph) {
            #pragma unroll
            for (int ct = 0; ct < 4; ++ct)
                #pragma unroll
                for (int it = 0; it < 4; ++it)
                    #pragma unroll
                    for (int r = 0; r < 4; ++r) {
                        int addr = (ct * 16 + lq * 4 + r) * 68 + it * 16 + lr;
                        if (ph == 0) obuf[addr]  = oa[ct][it][r];
                        else         obuf[addr] += oa[ct][it][r];
                    }
        }
        __syncthreads();
    }
    if (t < 64) {
        float l = lbuf[t] + lbuf[64 + t] + lbuf[128 + t] + lbuf[192 + t];
        lbuf[256 + t] = 1.f / l;
    }
    __syncthreads();

    // ---- epilogue: out = gamma*O/l + x ----
    const float g2 = gamma[0];
    const int c0 = cs * 64;
    const int cc = t >> 2;
    const int ic = (t & 3) * 16;
    const size_t rowbase = ((size_t)b * C_DIM + c0 + cc) * N_DIM + i0 + ic;
    #pragma unroll
    for (int k = 0; k < 4; ++k) {
        float4 ov4 = *(const float4*)&obuf[cc * 68 + ic + k * 4];
        float4 li  = *(const float4*)&lbuf[256 + ic + k * 4];
        float4 xv  = *(const float4*)(x + rowbase + k * 4);
        float4 ov;
        ov.x = g2 * ov4.x * li.x + xv.x;
        ov.y = g2 * ov4.y * li.y + xv.y;
        ov.z = g2 * ov4.z * li.z + xv.z;
        ov.w = g2 * ov4.w * li.w + xv.w;
        *(float4*)(out + rowbase + k * 4) = ov;
    }
}

extern "C" void kernel_launch(void* const* d_in, const int* in_sizes, int n_in,
                              void* d_out, int out_size, void* d_ws, size_t ws_size,
                              hipStream_t stream) {
    const float* x     = (const float*)d_in[0];
    const float* q_w   = (const float*)d_in[1];
    const float* q_b   = (const float*)d_in[2];
    const float* k_w   = (const float*)d_in[3];
    const float* k_b   = (const float*)d_in[4];
    const float* v_w   = (const float*)d_in[5];
    const float* v_b   = (const float*)d_in[6];
    const float* gamma = (const float*)d_in[7];
    float* out = (float*)d_out;

    char* ws = (char*)d_ws;
    unsigned short* qT    = (unsigned short*)(ws);             // 512KB
    unsigned short* kT    = (unsigned short*)(ws + 524288);    // 512KB
    unsigned short* vbf   = (unsigned short*)(ws + 1048576);   // 4MB (tiled)
    unsigned short* wbf   = (unsigned short*)(ws + 5242880);   // 160KB
    float*          biasf = (float*)(ws + 5406720);            // 1.25KB

    hipLaunchKernelGGL(wconv, dim3(320), dim3(256), 0, stream,
                       q_w, q_b, k_w, k_b, v_w, v_b, wbf, biasf);
    hipLaunchKernelGGL(qkv_proj, dim3(B_DIM * 128), dim3(256), 0, stream,
                       x, wbf, biasf, qT, kT, vbf);
    hipLaunchKernelGGL(attn_kernel, dim3(B_DIM * 64 * 4), dim3(256), 0, stream,
                       qT, kT, vbf, x, gamma, out);
}